// Round 1
// baseline (1533.984 us; speedup 1.0000x reference)
//
#include <hip/hip_runtime.h>
#include <cstdint>

#define NFEAT 128

// ---------------- degree / norm ----------------

__global__ void deg_init_k(int* __restrict__ deg, int n) {
    int i = blockIdx.x * blockDim.x + threadIdx.x;
    if (i < n) deg[i] = 1;  // self-loop
}

__global__ void deg_count_k(const int* __restrict__ dst, int E, int* __restrict__ deg) {
    int stride = gridDim.x * blockDim.x;
    for (int e = blockIdx.x * blockDim.x + threadIdx.x; e < E; e += stride)
        atomicAdd(&deg[dst[e]], 1);
}

__global__ void dinv_k(const int* __restrict__ deg, float* __restrict__ dinv, int n) {
    int i = blockIdx.x * blockDim.x + threadIdx.x;
    if (i < n) dinv[i] = rsqrtf((float)deg[i]);
}

// ---------------- fp32 GEMM: H = act(X) @ W  (X: [nrows,128], W: [128,128]) ----------------
// 64x64 tile per block, 256 threads as 16x16, 4x4 register tile, BK=64 two-phase LDS staging.

template <bool RELU>
__global__ __launch_bounds__(256) void gemm_k(const float* __restrict__ X,
                                              const float* __restrict__ W,
                                              float* __restrict__ H, int nrows) {
    __shared__ float xs[64 * 68];   // [row][k] pitch 68 (pad: conflict-free scalar col reads)
    __shared__ float wsh[64 * 68];  // [k][col] pitch 68 (float4 reads, 2-way max)
    const int t = threadIdx.x;
    const int tx = t & 15, ty = t >> 4;
    const int row0 = blockIdx.x * 64;
    const int col0 = blockIdx.y * 64;
    float acc[4][4] = {{0.f, 0.f, 0.f, 0.f}};

    for (int kp = 0; kp < 2; ++kp) {
        // stage X tile: 64 rows x 64 k  (16 float4 per row)
        for (int i = t; i < 64 * 16; i += 256) {
            int r = i >> 4, c = (i & 15) * 4;
            float4 v = make_float4(0.f, 0.f, 0.f, 0.f);
            if (row0 + r < nrows) {
                v = *(const float4*)(X + (size_t)(row0 + r) * NFEAT + kp * 64 + c);
                if (RELU) {
                    v.x = fmaxf(v.x, 0.f); v.y = fmaxf(v.y, 0.f);
                    v.z = fmaxf(v.z, 0.f); v.w = fmaxf(v.w, 0.f);
                }
            }
            *(float4*)&xs[r * 68 + c] = v;
        }
        // stage W tile: 64 k x 64 cols
        for (int i = t; i < 64 * 16; i += 256) {
            int k = i >> 4, c = (i & 15) * 4;
            float4 v = *(const float4*)(W + (size_t)(kp * 64 + k) * NFEAT + col0 + c);
            *(float4*)&wsh[k * 68 + c] = v;
        }
        __syncthreads();

#pragma unroll 8
        for (int k = 0; k < 64; ++k) {
            float a[4];
#pragma unroll
            for (int i = 0; i < 4; ++i) a[i] = xs[(ty * 4 + i) * 68 + k];
            float4 b = *(const float4*)&wsh[k * 68 + tx * 4];
#pragma unroll
            for (int i = 0; i < 4; ++i) {
                acc[i][0] = fmaf(a[i], b.x, acc[i][0]);
                acc[i][1] = fmaf(a[i], b.y, acc[i][1]);
                acc[i][2] = fmaf(a[i], b.z, acc[i][2]);
                acc[i][3] = fmaf(a[i], b.w, acc[i][3]);
            }
        }
        __syncthreads();
    }

#pragma unroll
    for (int i = 0; i < 4; ++i) {
        int r = row0 + ty * 4 + i;
        if (r < nrows)
            *(float4*)(H + (size_t)r * NFEAT + col0 + tx * 4) =
                make_float4(acc[i][0], acc[i][1], acc[i][2], acc[i][3]);
    }
}

// ---------------- aggregation ----------------
// init: out[i,f] = dinv[i]^2 * h[i,f] + bias[f]   (self-loop + bias folded in)
__global__ void agg_init_k(const float* __restrict__ h, const float* __restrict__ dinv,
                           const float* __restrict__ bias, float* __restrict__ out, int n) {
    int total4 = n * (NFEAT / 4);
    int stride = gridDim.x * blockDim.x;
    for (int idx = blockIdx.x * blockDim.x + threadIdx.x; idx < total4; idx += stride) {
        int node = idx >> 5;            // 32 float4 per node
        int c = (idx & 31) * 4;
        float di = dinv[node];
        float di2 = di * di;
        float4 hv = *(const float4*)(h + (size_t)node * NFEAT + c);
        float4 bv = *(const float4*)(bias + c);
        float4 o;
        o.x = fmaf(di2, hv.x, bv.x);
        o.y = fmaf(di2, hv.y, bv.y);
        o.z = fmaf(di2, hv.z, bv.z);
        o.w = fmaf(di2, hv.w, bv.w);
        *(float4*)(out + (size_t)node * NFEAT + c) = o;
    }
}

// edges: out[dst,f] += h[src,f] * dinv[src]*dinv[dst]   (128 threads per edge)
__global__ void agg_edge_k(const int* __restrict__ src, const int* __restrict__ dst,
                           const float* __restrict__ dinv, const float* __restrict__ h,
                           float* __restrict__ out, int E) {
    int f = threadIdx.x & 127;
    int eoff = threadIdx.x >> 7;  // 0 or 1: two edges per block iteration
    for (int e = blockIdx.x * 2 + eoff; e < E; e += gridDim.x * 2) {
        int s = src[e], d = dst[e];
        float w = dinv[s] * dinv[d];
        float v = h[(size_t)s * NFEAT + f] * w;
        atomicAdd(&out[(size_t)d * NFEAT + f], v);
    }
}

// ---------------- launch ----------------

extern "C" void kernel_launch(void* const* d_in, const int* in_sizes, int n_in,
                              void* d_out, int out_size, void* d_ws, size_t ws_size,
                              hipStream_t stream) {
    const float* x  = (const float*)d_in[0];
    const int*   ei = (const int*)d_in[1];   // [2, E] int32 (JAX downcasts int64 w/o x64)
    const float* W1 = (const float*)d_in[2];
    const float* b1 = (const float*)d_in[3];
    const float* W2 = (const float*)d_in[4];
    const float* b2 = (const float*)d_in[5];
    float* out = (float*)d_out;

    const int N = in_sizes[0] / NFEAT;
    const int E = in_sizes[1] / 2;
    const int* srcv = ei;
    const int* dstv = ei + E;

    // workspace: deg[N] int, dinv[N] float, hbuf[N*128] float  (~52 MB)
    char* wsp = (char*)d_ws;
    int*   deg  = (int*)wsp;
    float* dinv = (float*)(wsp + (size_t)N * 4);
    float* hbuf = (float*)(wsp + (size_t)N * 8);

    // degree + norm
    deg_init_k<<<(N + 255) / 256, 256, 0, stream>>>(deg, N);
    deg_count_k<<<2048, 256, 0, stream>>>(dstv, E, deg);
    dinv_k<<<(N + 255) / 256, 256, 0, stream>>>(deg, dinv, N);

    dim3 gemm_grid((N + 63) / 64, 2);

    // layer 1: h = x@W1 ; agg into d_out (used as scratch for h1)
    gemm_k<false><<<gemm_grid, 256, 0, stream>>>(x, W1, hbuf, N);
    agg_init_k<<<2048, 256, 0, stream>>>(hbuf, dinv, b1, out, N);
    agg_edge_k<<<8192, 256, 0, stream>>>(srcv, dstv, dinv, hbuf, out, E);

    // layer 2: h2 = relu(h1)@W2 (relu fused into gemm load); agg into d_out
    gemm_k<true><<<gemm_grid, 256, 0, stream>>>(out, W2, hbuf, N);
    agg_init_k<<<2048, 256, 0, stream>>>(hbuf, dinv, b2, out, N);
    agg_edge_k<<<8192, 256, 0, stream>>>(srcv, dstv, dinv, hbuf, out, E);
}

// Round 2
// 552.422 us; speedup vs baseline: 2.7768x; 2.7768x over previous
//
#include <hip/hip_runtime.h>
#include <cstdint>

#define NFEAT 128

// ---------------- small utility kernels ----------------

__global__ void zero_i_k(int* __restrict__ p, int n) {
    int i = blockIdx.x * blockDim.x + threadIdx.x;
    if (i < n) p[i] = 0;
}

__global__ void hist_k(const int* __restrict__ dst, int E, int* __restrict__ cnt) {
    int stride = gridDim.x * blockDim.x;
    for (int e = blockIdx.x * blockDim.x + threadIdx.x; e < E; e += stride)
        atomicAdd(&cnt[dst[e]], 1);
}

// dinv = rsqrt(1 + cnt)   (self-loop included in degree)
__global__ void dinv_k(const int* __restrict__ cnt, float* __restrict__ dinv, int n) {
    int i = blockIdx.x * blockDim.x + threadIdx.x;
    if (i < n) dinv[i] = rsqrtf((float)(1 + cnt[i]));
}

// ---------------- 3-kernel exclusive scan (N <= 512*256) ----------------

__global__ void scan_block_k(const int* __restrict__ cnt, int* __restrict__ outv,
                             int* __restrict__ bsum, int N) {
    __shared__ int s[256];
    int i = blockIdx.x * 256 + threadIdx.x;
    int v = (i < N) ? cnt[i] : 0;
    s[threadIdx.x] = v;
    __syncthreads();
    for (int off = 1; off < 256; off <<= 1) {
        int t = (threadIdx.x >= off) ? s[threadIdx.x - off] : 0;
        __syncthreads();
        s[threadIdx.x] += t;
        __syncthreads();
    }
    if (i < N) outv[i] = s[threadIdx.x] - v;  // exclusive
    if (threadIdx.x == 255) bsum[blockIdx.x] = s[255];
}

__global__ void scan_top_k(int* __restrict__ bsum, int nb) {
    __shared__ int s[512];
    int v = (threadIdx.x < nb) ? bsum[threadIdx.x] : 0;
    s[threadIdx.x] = v;
    __syncthreads();
    for (int off = 1; off < 512; off <<= 1) {
        int t = (threadIdx.x >= off) ? s[threadIdx.x - off] : 0;
        __syncthreads();
        s[threadIdx.x] += t;
        __syncthreads();
    }
    if (threadIdx.x < nb) bsum[threadIdx.x] = s[threadIdx.x] - v;  // exclusive
}

__global__ void scan_add_k(int* __restrict__ rowptr, const int* __restrict__ bsum,
                           int N, int E) {
    int i = blockIdx.x * 256 + threadIdx.x;
    if (i < N) rowptr[i] += bsum[blockIdx.x];
    if (i == 0) rowptr[N] = E;
}

// ---------------- CSR scatter ----------------

__global__ void scatter_k(const int* __restrict__ src, const int* __restrict__ dst,
                          const int* __restrict__ rowptr, int* __restrict__ fill,
                          int* __restrict__ csr_src, int E) {
    int stride = gridDim.x * blockDim.x;
    for (int e = blockIdx.x * blockDim.x + threadIdx.x; e < E; e += stride) {
        int d = dst[e];
        int pos = rowptr[d] + atomicAdd(&fill[d], 1);
        csr_src[pos] = src[e];
    }
}

// ---------------- fp32 GEMM: H = act(X) @ W  (X: [nrows,128], W: [128,128]) ----------------

template <bool RELU>
__global__ __launch_bounds__(256) void gemm_k(const float* __restrict__ X,
                                              const float* __restrict__ W,
                                              float* __restrict__ H, int nrows) {
    __shared__ float xs[64 * 68];
    __shared__ float wsh[64 * 68];
    const int t = threadIdx.x;
    const int tx = t & 15, ty = t >> 4;
    const int row0 = blockIdx.x * 64;
    const int col0 = blockIdx.y * 64;
    float acc[4][4] = {{0.f, 0.f, 0.f, 0.f}};

    for (int kp = 0; kp < 2; ++kp) {
        for (int i = t; i < 64 * 16; i += 256) {
            int r = i >> 4, c = (i & 15) * 4;
            float4 v = make_float4(0.f, 0.f, 0.f, 0.f);
            if (row0 + r < nrows) {
                v = *(const float4*)(X + (size_t)(row0 + r) * NFEAT + kp * 64 + c);
                if (RELU) {
                    v.x = fmaxf(v.x, 0.f); v.y = fmaxf(v.y, 0.f);
                    v.z = fmaxf(v.z, 0.f); v.w = fmaxf(v.w, 0.f);
                }
            }
            *(float4*)&xs[r * 68 + c] = v;
        }
        for (int i = t; i < 64 * 16; i += 256) {
            int k = i >> 4, c = (i & 15) * 4;
            float4 v = *(const float4*)(W + (size_t)(kp * 64 + k) * NFEAT + col0 + c);
            *(float4*)&wsh[k * 68 + c] = v;
        }
        __syncthreads();

#pragma unroll 8
        for (int k = 0; k < 64; ++k) {
            float a[4];
#pragma unroll
            for (int i = 0; i < 4; ++i) a[i] = xs[(ty * 4 + i) * 68 + k];
            float4 b = *(const float4*)&wsh[k * 68 + tx * 4];
#pragma unroll
            for (int i = 0; i < 4; ++i) {
                acc[i][0] = fmaf(a[i], b.x, acc[i][0]);
                acc[i][1] = fmaf(a[i], b.y, acc[i][1]);
                acc[i][2] = fmaf(a[i], b.z, acc[i][2]);
                acc[i][3] = fmaf(a[i], b.w, acc[i][3]);
            }
        }
        __syncthreads();
    }

#pragma unroll
    for (int i = 0; i < 4; ++i) {
        int r = row0 + ty * 4 + i;
        if (r < nrows)
            *(float4*)(H + (size_t)r * NFEAT + col0 + tx * 4) =
                make_float4(acc[i][0], acc[i][1], acc[i][2], acc[i][3]);
    }
}

// ---------------- CSR aggregation: one wave per node ----------------
// out[d,:] = sum_{e in CSR[d]} dinv[src]*dinv[d]*h[src,:] + dinv[d]^2*h[d,:] + bias

__global__ __launch_bounds__(256) void agg_csr_k(const int* __restrict__ rowptr,
                                                 const int* __restrict__ csr_src,
                                                 const float* __restrict__ dinv,
                                                 const float* __restrict__ h,
                                                 const float* __restrict__ bias,
                                                 float* __restrict__ out, int N) {
    int node = (int)((blockIdx.x * (unsigned)blockDim.x + threadIdx.x) >> 6);
    int lane = threadIdx.x & 63;
    if (node >= N) return;
    float dd = dinv[node];
    int p0 = rowptr[node], p1 = rowptr[node + 1];
    float a0 = 0.f, a1 = 0.f, b0 = 0.f, b1 = 0.f;
    int p = p0;
    for (; p + 2 <= p1; p += 2) {
        int s0 = csr_src[p], s1 = csr_src[p + 1];
        float w0 = dinv[s0] * dd, w1 = dinv[s1] * dd;
        a0 = fmaf(w0, h[(size_t)s0 * NFEAT + lane], a0);
        a1 = fmaf(w0, h[(size_t)s0 * NFEAT + 64 + lane], a1);
        b0 = fmaf(w1, h[(size_t)s1 * NFEAT + lane], b0);
        b1 = fmaf(w1, h[(size_t)s1 * NFEAT + 64 + lane], b1);
    }
    if (p < p1) {
        int s0 = csr_src[p];
        float w0 = dinv[s0] * dd;
        a0 = fmaf(w0, h[(size_t)s0 * NFEAT + lane], a0);
        a1 = fmaf(w0, h[(size_t)s0 * NFEAT + 64 + lane], a1);
    }
    float wl = dd * dd;
    a0 = fmaf(wl, h[(size_t)node * NFEAT + lane], a0 + b0);
    a1 = fmaf(wl, h[(size_t)node * NFEAT + 64 + lane], a1 + b1);
    out[(size_t)node * NFEAT + lane] = a0 + bias[lane];
    out[(size_t)node * NFEAT + 64 + lane] = a1 + bias[64 + lane];
}

// ---------------- launch ----------------

extern "C" void kernel_launch(void* const* d_in, const int* in_sizes, int n_in,
                              void* d_out, int out_size, void* d_ws, size_t ws_size,
                              hipStream_t stream) {
    const float* x  = (const float*)d_in[0];
    const int*   ei = (const int*)d_in[1];
    const float* W1 = (const float*)d_in[2];
    const float* b1 = (const float*)d_in[3];
    const float* W2 = (const float*)d_in[4];
    const float* b2 = (const float*)d_in[5];
    float* out = (float*)d_out;

    const int N = in_sizes[0] / NFEAT;
    const int E = in_sizes[1] / 2;
    const int* srcv = ei;
    const int* dstv = ei + E;

    // workspace layout
    char* wsp = (char*)d_ws;
    size_t off = 0;
    float* dinv    = (float*)(wsp + off); off += (size_t)N * 4;
    int*   rowptr  = (int*)(wsp + off);   off += (size_t)(N + 1) * 4;
    int*   bsum    = (int*)(wsp + off);   off += 512 * 4;
    int*   cnt     = (int*)(wsp + off);   off += (size_t)N * 4;   // also reused as fill
    int*   csr_src = (int*)(wsp + off);   off += (size_t)E * 4;
    off = (off + 255) & ~(size_t)255;
    float* hbuf    = (float*)(wsp + off); off += (size_t)N * NFEAT * 4;

    const int nb = (N + 255) / 256;  // scan blocks (391 <= 512)

    // --- degree + norm + CSR build ---
    zero_i_k<<<nb, 256, 0, stream>>>(cnt, N);
    hist_k<<<2048, 256, 0, stream>>>(dstv, E, cnt);
    dinv_k<<<nb, 256, 0, stream>>>(cnt, dinv, N);
    scan_block_k<<<nb, 256, 0, stream>>>(cnt, rowptr, bsum, N);
    scan_top_k<<<1, 512, 0, stream>>>(bsum, nb);
    scan_add_k<<<nb, 256, 0, stream>>>(rowptr, bsum, N, E);
    zero_i_k<<<nb, 256, 0, stream>>>(cnt, N);  // cnt -> fill
    scatter_k<<<2048, 256, 0, stream>>>(srcv, dstv, rowptr, cnt, csr_src, E);

    dim3 gemm_grid((N + 63) / 64, 2);
    const int agg_blocks = (N * 64 + 255) / 256;  // one wave per node

    // layer 1
    gemm_k<false><<<gemm_grid, 256, 0, stream>>>(x, W1, hbuf, N);
    agg_csr_k<<<agg_blocks, 256, 0, stream>>>(rowptr, csr_src, dinv, hbuf, b1, out, N);

    // layer 2 (ReLU fused into GEMM input load)
    gemm_k<true><<<gemm_grid, 256, 0, stream>>>(out, W2, hbuf, N);
    agg_csr_k<<<agg_blocks, 256, 0, stream>>>(rowptr, csr_src, dinv, hbuf, b2, out, N);
}

// Round 3
// 409.591 us; speedup vs baseline: 3.7452x; 1.3487x over previous
//
#include <hip/hip_runtime.h>
#include <cstdint>

#define NFEAT 128

typedef _Float16 half8 __attribute__((ext_vector_type(8)));
typedef _Float16 half2t __attribute__((ext_vector_type(2)));
typedef float f32x4 __attribute__((ext_vector_type(4)));

// ---------------- small utility kernels ----------------

__global__ void zero_i_k(int* __restrict__ p, int n) {
    int i = blockIdx.x * blockDim.x + threadIdx.x;
    if (i < n) p[i] = 0;
}

__global__ void hist_k(const int* __restrict__ dst, int E, int* __restrict__ cnt) {
    int stride = gridDim.x * blockDim.x;
    for (int e = blockIdx.x * blockDim.x + threadIdx.x; e < E; e += stride)
        atomicAdd(&cnt[dst[e]], 1);
}

__global__ void dinv_k(const int* __restrict__ cnt, float* __restrict__ dinv, int n) {
    int i = blockIdx.x * blockDim.x + threadIdx.x;
    if (i < n) dinv[i] = rsqrtf((float)(1 + cnt[i]));
}

// ---------------- 3-kernel exclusive scan ----------------

__global__ void scan_block_k(const int* __restrict__ cnt, int* __restrict__ outv,
                             int* __restrict__ bsum, int N) {
    __shared__ int s[256];
    int i = blockIdx.x * 256 + threadIdx.x;
    int v = (i < N) ? cnt[i] : 0;
    s[threadIdx.x] = v;
    __syncthreads();
    for (int off = 1; off < 256; off <<= 1) {
        int t = (threadIdx.x >= off) ? s[threadIdx.x - off] : 0;
        __syncthreads();
        s[threadIdx.x] += t;
        __syncthreads();
    }
    if (i < N) outv[i] = s[threadIdx.x] - v;
    if (threadIdx.x == 255) bsum[blockIdx.x] = s[255];
}

__global__ void scan_top_k(int* __restrict__ bsum, int nb) {
    __shared__ int s[512];
    int v = (threadIdx.x < nb) ? bsum[threadIdx.x] : 0;
    s[threadIdx.x] = v;
    __syncthreads();
    for (int off = 1; off < 512; off <<= 1) {
        int t = (threadIdx.x >= off) ? s[threadIdx.x - off] : 0;
        __syncthreads();
        s[threadIdx.x] += t;
        __syncthreads();
    }
    if (threadIdx.x < nb) bsum[threadIdx.x] = s[threadIdx.x] - v;
}

__global__ void scan_add_k(int* __restrict__ rowptr, const int* __restrict__ bsum,
                           int N, int E) {
    int i = blockIdx.x * 256 + threadIdx.x;
    if (i < N) rowptr[i] += bsum[blockIdx.x];
    if (i == 0) rowptr[N] = E;
}

__global__ void scatter_k(const int* __restrict__ src, const int* __restrict__ dst,
                          const int* __restrict__ rowptr, int* __restrict__ fill,
                          int* __restrict__ csr_src, int E) {
    int stride = gridDim.x * blockDim.x;
    for (int e = blockIdx.x * blockDim.x + threadIdx.x; e < E; e += stride) {
        int d = dst[e];
        int pos = rowptr[d] + atomicAdd(&fill[d], 1);
        csr_src[pos] = src[e];
    }
}

// W [128][128] fp32 -> WT [n][k] f16
__global__ void wtrans_k(const float* __restrict__ W, _Float16* __restrict__ WT) {
    int idx = blockIdx.x * 256 + threadIdx.x;   // 64 blocks
    int n = idx >> 7, k = idx & 127;
    WT[idx] = (_Float16)W[k * NFEAT + n];
}

// ---------------- MFMA f16 GEMM: H = X @ W  (H f16 [nrows,128]) ----------------
// 128-row tile, full N=128, full K=128 single stage. 4 waves, each owns 64x64.
// LDS: A [128][128] f16 (32KB, XOR-swizzled), B=WT [128][128] f16 (32KB, swizzled).

template <bool SRC_F16>
__global__ __launch_bounds__(256) void gemm_mfma_k(const void* __restrict__ Xv,
                                                   const _Float16* __restrict__ WT,
                                                   _Float16* __restrict__ H, int nrows) {
    __shared__ uint4 ldsbuf[4096];  // 64 KB
    char* ldsA = (char*)ldsbuf;
    char* ldsB = (char*)ldsbuf + 32768;
    const int t = threadIdx.x;
    const int row0 = blockIdx.x * 128;

    // stage A: 2048 chunks of 16B (8 f16); chunk = row*16 + cb
#pragma unroll
    for (int i = 0; i < 8; ++i) {
        int chunk = i * 256 + t;
        int r = chunk >> 4, cb = chunk & 15;
        half8 hv;
        if (row0 + r < nrows) {
            if (SRC_F16) {
                hv = *(const half8*)((const _Float16*)Xv + (size_t)(row0 + r) * NFEAT + cb * 8);
            } else {
                const float* X = (const float*)Xv;
                float4 v0 = *(const float4*)(X + (size_t)(row0 + r) * NFEAT + cb * 8);
                float4 v1 = *(const float4*)(X + (size_t)(row0 + r) * NFEAT + cb * 8 + 4);
                hv[0] = (_Float16)v0.x; hv[1] = (_Float16)v0.y;
                hv[2] = (_Float16)v0.z; hv[3] = (_Float16)v0.w;
                hv[4] = (_Float16)v1.x; hv[5] = (_Float16)v1.y;
                hv[6] = (_Float16)v1.z; hv[7] = (_Float16)v1.w;
            }
        } else {
            hv = (half8)(_Float16)0.f;
        }
        int byte = (r * 256 + cb * 16) ^ ((r & 7) << 4);
        *(half8*)(ldsA + byte) = hv;
    }
    // stage B (WT f16, no guard)
#pragma unroll
    for (int i = 0; i < 8; ++i) {
        int chunk = i * 256 + t;
        int r = chunk >> 4, cb = chunk & 15;
        half8 hv = *(const half8*)(WT + (size_t)r * NFEAT + cb * 8);
        int byte = (r * 256 + cb * 16) ^ ((r & 7) << 4);
        *(half8*)(ldsB + byte) = hv;
    }
    __syncthreads();

    const int w = t >> 6, lane = t & 63;
    const int wr = w >> 1, wc = w & 1;
    const int lrow = lane & 15, kgrp = lane >> 4;

    f32x4 acc[4][4];
#pragma unroll
    for (int m = 0; m < 4; ++m)
#pragma unroll
        for (int n = 0; n < 4; ++n) acc[m][n] = (f32x4)0.f;

#pragma unroll
    for (int kk = 0; kk < 4; ++kk) {
        int kb = (kk * 32 + kgrp * 8) * 2;  // byte col offset
        half8 a[4], b[4];
#pragma unroll
        for (int m = 0; m < 4; ++m) {
            int r = wr * 64 + m * 16 + lrow;
            a[m] = *(const half8*)(ldsA + ((r * 256 + kb) ^ ((r & 7) << 4)));
        }
#pragma unroll
        for (int n = 0; n < 4; ++n) {
            int c = wc * 64 + n * 16 + lrow;
            b[n] = *(const half8*)(ldsB + ((c * 256 + kb) ^ ((c & 7) << 4)));
        }
#pragma unroll
        for (int m = 0; m < 4; ++m)
#pragma unroll
            for (int n = 0; n < 4; ++n)
                acc[m][n] = __builtin_amdgcn_mfma_f32_16x16x32_f16(a[m], b[n], acc[m][n], 0, 0, 0);
    }

    // epilogue: C/D layout col=lane&15, row=(lane>>4)*4+reg
#pragma unroll
    for (int m = 0; m < 4; ++m) {
#pragma unroll
        for (int j = 0; j < 4; ++j) {
            int row = row0 + wr * 64 + m * 16 + kgrp * 4 + j;
            if (row < nrows) {
#pragma unroll
                for (int n = 0; n < 4; ++n)
                    H[(size_t)row * NFEAT + wc * 64 + n * 16 + lrow] = (_Float16)acc[m][n][j];
            }
        }
    }
}

// ---------------- CSR aggregation, f16 gather: one wave per node ----------------
// LAYER1: out f16 with ReLU(acc+bias); LAYER2: out fp32 acc+bias.

template <bool FINAL>
__global__ __launch_bounds__(256) void agg_csr_k(const int* __restrict__ rowptr,
                                                 const int* __restrict__ csr_src,
                                                 const float* __restrict__ dinv,
                                                 const _Float16* __restrict__ h,
                                                 const float* __restrict__ bias,
                                                 void* __restrict__ outv, int N) {
    int node = (int)((blockIdx.x * (unsigned)blockDim.x + threadIdx.x) >> 6);
    int lane = threadIdx.x & 63;
    if (node >= N) return;
    float dd = dinv[node];
    int p0 = rowptr[node], p1 = rowptr[node + 1];
    float a0 = 0.f, a1 = 0.f, b0 = 0.f, b1 = 0.f;
    int p = p0;
    for (; p + 2 <= p1; p += 2) {
        int s0 = csr_src[p], s1 = csr_src[p + 1];
        float w0 = dinv[s0] * dd, w1 = dinv[s1] * dd;
        half2t h0 = *(const half2t*)(h + (size_t)s0 * NFEAT + lane * 2);
        half2t h1 = *(const half2t*)(h + (size_t)s1 * NFEAT + lane * 2);
        a0 = fmaf(w0, (float)h0[0], a0);
        a1 = fmaf(w0, (float)h0[1], a1);
        b0 = fmaf(w1, (float)h1[0], b0);
        b1 = fmaf(w1, (float)h1[1], b1);
    }
    if (p < p1) {
        int s0 = csr_src[p];
        float w0 = dinv[s0] * dd;
        half2t h0 = *(const half2t*)(h + (size_t)s0 * NFEAT + lane * 2);
        a0 = fmaf(w0, (float)h0[0], a0);
        a1 = fmaf(w0, (float)h0[1], a1);
    }
    float wl = dd * dd;
    half2t hs = *(const half2t*)(h + (size_t)node * NFEAT + lane * 2);
    a0 = fmaf(wl, (float)hs[0], a0 + b0);
    a1 = fmaf(wl, (float)hs[1], a1 + b1);
    float2 bv = *(const float2*)(bias + lane * 2);
    a0 += bv.x;
    a1 += bv.y;
    if (FINAL) {
        float* out = (float*)outv;
        *(float2*)(out + (size_t)node * NFEAT + lane * 2) = make_float2(a0, a1);
    } else {
        _Float16* out = (_Float16*)outv;
        half2t o;
        o[0] = (_Float16)fmaxf(a0, 0.f);
        o[1] = (_Float16)fmaxf(a1, 0.f);
        *(half2t*)(out + (size_t)node * NFEAT + lane * 2) = o;
    }
}

// ---------------- launch ----------------

extern "C" void kernel_launch(void* const* d_in, const int* in_sizes, int n_in,
                              void* d_out, int out_size, void* d_ws, size_t ws_size,
                              hipStream_t stream) {
    const float* x  = (const float*)d_in[0];
    const int*   ei = (const int*)d_in[1];
    const float* W1 = (const float*)d_in[2];
    const float* b1 = (const float*)d_in[3];
    const float* W2 = (const float*)d_in[4];
    const float* b2 = (const float*)d_in[5];
    float* out = (float*)d_out;

    const int N = in_sizes[0] / NFEAT;
    const int E = in_sizes[1] / 2;
    const int* srcv = ei;
    const int* dstv = ei + E;

    // workspace layout (256B-aligned slices)
    char* wsp = (char*)d_ws;
    size_t off = 0;
    auto alloc = [&](size_t bytes) {
        char* p = wsp + off;
        off = (off + bytes + 255) & ~(size_t)255;
        return p;
    };
    float*    dinv    = (float*)alloc((size_t)N * 4);
    int*      rowptr  = (int*)alloc((size_t)(N + 1) * 4);
    int*      bsum    = (int*)alloc(512 * 4);
    int*      cnt     = (int*)alloc((size_t)N * 4);       // reused as fill
    int*      csr_src = (int*)alloc((size_t)E * 4);
    _Float16* wt1     = (_Float16*)alloc(NFEAT * NFEAT * 2);
    _Float16* wt2     = (_Float16*)alloc(NFEAT * NFEAT * 2);
    _Float16* hbuf    = (_Float16*)alloc((size_t)N * NFEAT * 2);
    _Float16* a1buf   = (_Float16*)alloc((size_t)N * NFEAT * 2);

    const int nb = (N + 255) / 256;

    // degree + norm + CSR build
    zero_i_k<<<nb, 256, 0, stream>>>(cnt, N);
    hist_k<<<2048, 256, 0, stream>>>(dstv, E, cnt);
    dinv_k<<<nb, 256, 0, stream>>>(cnt, dinv, N);
    scan_block_k<<<nb, 256, 0, stream>>>(cnt, rowptr, bsum, N);
    scan_top_k<<<1, 512, 0, stream>>>(bsum, nb);
    scan_add_k<<<nb, 256, 0, stream>>>(rowptr, bsum, N, E);
    zero_i_k<<<nb, 256, 0, stream>>>(cnt, N);
    scatter_k<<<2048, 256, 0, stream>>>(srcv, dstv, rowptr, cnt, csr_src, E);

    // weight transpose+cast
    wtrans_k<<<64, 256, 0, stream>>>(W1, wt1);
    wtrans_k<<<64, 256, 0, stream>>>(W2, wt2);

    const int gemm_blocks = (N + 127) / 128;
    const int agg_blocks = (int)(((size_t)N * 64 + 255) / 256);

    // layer 1: h1 = x@W1 (f16) ; a1 = relu(Agg(h1)+b1) (f16)
    gemm_mfma_k<false><<<gemm_blocks, 256, 0, stream>>>(x, wt1, hbuf, N);
    agg_csr_k<false><<<agg_blocks, 256, 0, stream>>>(rowptr, csr_src, dinv, hbuf, b1, a1buf, N);

    // layer 2: h2 = a1@W2 (f16) ; out = Agg(h2)+b2 (fp32)
    gemm_mfma_k<true><<<gemm_blocks, 256, 0, stream>>>(a1buf, wt2, hbuf, N);
    agg_csr_k<true><<<agg_blocks, 256, 0, stream>>>(rowptr, csr_src, dinv, hbuf, b2, out, N);
}